// Round 6
// baseline (404.793 us; speedup 1.0000x reference)
//
#include <hip/hip_runtime.h>
#include <hip/hip_bf16.h>
#include <stdint.h>

using f32x4  = __attribute__((ext_vector_type(4))) float;
using f32x16 = __attribute__((ext_vector_type(16))) float;
using bf16x8 = __attribute__((ext_vector_type(8))) short;

constexpr int BATCH = 4;
constexpr int LQ_   = 256;
constexpr int LK_   = 50000;
constexpr int OUTD  = 256;
constexpr int EIN   = 128;
constexpr int TKB   = 32;                     // k-rows per tile
constexpr int NKT   = (LK_ + TKB - 1) / TKB;  // 1563
constexpr int BPB   = 64;                     // blocks per batch (grid = 256)

__device__ __forceinline__ uint32_t f2bf(float f) {
  uint32_t u = __builtin_bit_cast(uint32_t, f);
  u = (u + 0x7fffu + ((u >> 16) & 1u)) >> 16;
  return u;
}

// LDS-only barrier: drains this wave's LDS ops, then raw s_barrier.
// Crucially does NOT drain vmcnt -> in-flight global loads survive barriers.
__device__ __forceinline__ void block_sync_lds() {
  asm volatile("s_waitcnt lgkmcnt(0)" ::: "memory");
  __builtin_amdgcn_sched_barrier(0);
  __builtin_amdgcn_s_barrier();
  __builtin_amdgcn_sched_barrier(0);
}

// ---- prep_all: blocks 0-63 -> Gn, 64-95 -> cast Wv, 96 -> zero num/den ----
__global__ __launch_bounds__(256) void prep_all(
    const float* __restrict__ query, const float* __restrict__ Wq,
    const float* __restrict__ bq,    const float* __restrict__ Wk,
    const float* __restrict__ Wv,    ushort* __restrict__ Gn,
    ushort* __restrict__ Wvbf,       float* __restrict__ numden)
{
  const int blk = blockIdx.x, tid = threadIdx.x;
  if (blk >= 64) {
    if (blk < 96) {                       // cast Wv -> bf16 (32 blocks x 2048)
      int base = (blk - 64) * 2048 + tid * 8;
      float4 a = *(const float4*)(Wv + base);
      float4 c = *(const float4*)(Wv + base + 4);
      uint4 pk;
      pk.x = f2bf(a.x) | (f2bf(a.y) << 16);
      pk.y = f2bf(a.z) | (f2bf(a.w) << 16);
      pk.z = f2bf(c.x) | (f2bf(c.y) << 16);
      pk.w = f2bf(c.z) | (f2bf(c.w) << 16);
      *(uint4*)(Wvbf + base) = pk;
    } else {                              // zero the atomic accumulators
      for (int i = tid; i < 2 * BATCH * OUTD; i += 256) numden[i] = 0.f;
    }
    return;
  }
  // ---- Gn[b] = (1/16)*(query[b]@Wq^T + bq)@Wk, 16 q-rows per block -------
  __shared__ float qin[16 * EIN];
  __shared__ float Qr [16 * OUTD];
  const int b = blk >> 4, q0 = (blk & 15) * 16;
  {
    int idx = tid * 8;
    int row = idx >> 7, c = idx & 127;
    const float* p = query + ((size_t)b * LQ_ + q0 + row) * EIN + c;
    float4 a = *(const float4*)p;
    float4 d = *(const float4*)(p + 4);
    float* q = &qin[row * EIN + c];
    q[0]=a.x; q[1]=a.y; q[2]=a.z; q[3]=a.w; q[4]=d.x; q[5]=d.y; q[6]=d.z; q[7]=d.w;
  }
  __syncthreads();

  float acc[16];
  {
    float bias = bq[tid];
#pragma unroll
    for (int i = 0; i < 16; ++i) acc[i] = bias;
  }
  for (int d4 = 0; d4 < EIN / 4; ++d4) {
    f32x4 w4 = *(const f32x4*)(Wq + tid * EIN + d4 * 4);
#pragma unroll
    for (int i = 0; i < 16; ++i) {
      f32x4 q4 = *(const f32x4*)(qin + i * EIN + d4 * 4);
      acc[i] += q4[0]*w4[0] + q4[1]*w4[1] + q4[2]*w4[2] + q4[3]*w4[3];
    }
  }
#pragma unroll
  for (int i = 0; i < 16; ++i) Qr[i * OUTD + tid] = acc[i];
  __syncthreads();

  float acc2[16];
#pragma unroll
  for (int i = 0; i < 16; ++i) acc2[i] = 0.f;
  for (int d4 = 0; d4 < OUTD / 4; ++d4) {
    float w0 = Wk[(d4*4+0) * OUTD + tid];
    float w1 = Wk[(d4*4+1) * OUTD + tid];
    float w2 = Wk[(d4*4+2) * OUTD + tid];
    float w3 = Wk[(d4*4+3) * OUTD + tid];
#pragma unroll
    for (int i = 0; i < 16; ++i) {
      f32x4 q4 = *(const f32x4*)(Qr + i * OUTD + d4 * 4);
      acc2[i] += q4[0]*w0 + q4[1]*w1 + q4[2]*w2 + q4[3]*w3;
    }
  }
  const float norm = 0.0625f;
#pragma unroll
  for (int i = 0; i < 16; ++i)
    Gn[((size_t)b * LQ_ + q0 + i) * OUTD + tid] = (ushort)f2bf(acc2[i] * norm);
}

// ---- main ------------------------------------------------------------------
// 256 blocks (1/CU), 1024 thr = 16 waves, S/V split (waves 0-7: Gn/S/exp/den;
// waves 8-15: Wv/Vt/num). A-frags pinned in VGPRs via asm (64 regs), total
// ~120 < 128 cap -> 16 waves/CU resident. Raw lgkm-only barriers keep global
// loads in flight across barriers; staging issued a full iteration ahead.
__global__ __launch_bounds__(1024, 4) void attn_main(
    const float*  __restrict__ input, const ushort* __restrict__ Gn,
    const ushort* __restrict__ Wvbf,  float* __restrict__ num,
    float* __restrict__ den)
{
  __shared__ ushort bb[2 * 8192];     // 2 x 16 KB bf16 input tile
  __shared__ float  etile[8192];      // 32 KB: [wq][r4][lane] f32
  const int b = blockIdx.x >> 6, blk = blockIdx.x & (BPB - 1);
  const int t0 = (blk * NKT) >> 6, t1 = ((blk + 1) * NKT) >> 6;
  const int tid = threadIdx.x, w = tid >> 6, l = tid & 63;
  const int wq = w & 7;
  const bool isS = (w < 8);
  const int hi = l >> 5, lk = l & 31;
  const float* src = input + (size_t)b * LK_ * 256;

  // persistent A-fragments: one matrix per wave (64 VGPRs), PINNED
  const int arow = wq * 32 + lk;
  const ushort* ap = (isS ? (Gn + ((size_t)b * LQ_ + arow) * 256)
                          : (Wvbf + (size_t)arow * 256)) + hi * 8;
  bf16x8 af[16];
#pragma unroll
  for (int k = 0; k < 16; ++k) {
    af[k] = *(const bf16x8*)(ap + k * 16);
    asm volatile("" : "+v"(af[k]));   // force residency: value is asm-defined
  }

  float accR[16];
#pragma unroll
  for (int r = 0; r < 16; ++r) accR[r] = 0.f;

  float4 sA0, sA1;                    // staging regs (8 f32 / thread)
  auto loadreg = [&](int t) {
    int row = t * TKB + (tid >> 5);
    row = row < LK_ ? row : LK_ - 1;  // clamp (masked via e=0)
    const float* p = src + (size_t)row * 256 + (tid & 31) * 8;
    sA0 = *(const float4*)p;
    sA1 = *(const float4*)(p + 4);
  };
  auto writebuf = [&](int buf) {
    int fb = tid & 31, row = tid >> 5;
    uint4 pk;
    pk.x = f2bf(sA0.x) | (f2bf(sA0.y) << 16);
    pk.y = f2bf(sA0.z) | (f2bf(sA0.w) << 16);
    pk.z = f2bf(sA1.x) | (f2bf(sA1.y) << 16);
    pk.w = f2bf(sA1.z) | (f2bf(sA1.w) << 16);
    *(uint4*)((char*)bb + buf * 16384 + fb * 512 + ((row ^ fb) * 16)) = pk;
  };

  loadreg(t0);
  writebuf(0);
  loadreg(t0 + 1);                    // in flight across the barrier below
  block_sync_lds();

  char* emy = (char*)etile + wq * 4096 + l * 16;

  for (int t = t0; t < t1; ++t) {
    const int p = (t - t0) & 1;
    // TOP: drain year-old loads (t+1) into the spare buffer, issue t+2.
    // Writes to buf p^1 are 2 barriers past its last reader (iter t-1 MFMA).
    if (t + 1 < t1) {
      writebuf(p ^ 1);                // vmcnt wait hits loads issued last iter
      if (t + 2 < t1) loadreg(t + 2); // full iteration to land
    }

    const char* base = (const char*)bb + p * 16384;
    f32x16 aX = {0,0,0,0,0,0,0,0,0,0,0,0,0,0,0,0};
#pragma unroll
    for (int ks = 0; ks < 16; ++ks) {
      const int fb = ks * 2 + hi;
      bf16x8 bv = *(const bf16x8*)(base + fb * 512 + ((lk ^ fb) * 16));
      aX = __builtin_amdgcn_mfma_f32_32x32x16_bf16(af[ks], bv, aX, 0, 0, 0);
    }

    if (isS) {
      const bool valid = (t * TKB + lk) < LK_;
#pragma unroll
      for (int r4 = 0; r4 < 4; ++r4) {
        f32x4 ev;
#pragma unroll
        for (int j = 0; j < 4; ++j) {
          float e = valid ? __expf(aX[r4 * 4 + j]) : 0.f;
          ev[j] = e;
          accR[r4 * 4 + j] += e;
        }
        *(f32x4*)(emy + r4 * 1024) = ev;
      }
    }
    block_sync_lds();                 // A: e published; bb(t) fully consumed

    if (!isS) {
#pragma unroll
      for (int r4 = 0; r4 < 4; ++r4) {
        f32x4 ev = *(const f32x4*)(emy + r4 * 1024);
#pragma unroll
        for (int j = 0; j < 4; ++j)
          accR[r4 * 4 + j] += ev[j] * aX[r4 * 4 + j];
      }
    }
    block_sync_lds();                 // B: bb(t+1)/etile safe to reuse
  }

  // reduce over 32 k-lanes, one atomic per q
#pragma unroll
  for (int r = 0; r < 16; ++r) {
    float v = accR[r];
#pragma unroll
    for (int m = 1; m < 32; m <<= 1) v += __shfl_xor(v, m, 64);
    if (lk == 0) {
      int q = wq * 32 + 4 * hi + (r & 3) + 8 * (r >> 2);
      atomicAdd((isS ? den : num) + b * OUTD + q, v);
    }
  }
}

// ---- finalize: out = num/den + bv ------------------------------------------
__global__ __launch_bounds__(256) void finalize(const float* __restrict__ num,
                                                const float* __restrict__ den,
                                                const float* __restrict__ bv,
                                                float* __restrict__ out) {
  int i = blockIdx.x * 256 + threadIdx.x;
  out[i] = num[i] / den[i] + bv[i & 255];
}

extern "C" void kernel_launch(void* const* d_in, const int* in_sizes, int n_in,
                              void* d_out, int out_size, void* d_ws, size_t ws_size,
                              hipStream_t stream)
{
  const float* query = (const float*)d_in[0];
  const float* input = (const float*)d_in[1];
  const float* Wq    = (const float*)d_in[2];
  const float* bq    = (const float*)d_in[3];
  const float* Wk    = (const float*)d_in[4];
  // d_in[5] = bk : softmax-invariant, unused
  const float* Wv    = (const float*)d_in[6];
  const float* bv    = (const float*)d_in[7];
  float* out = (float*)d_out;

  char* ws = (char*)d_ws;
  ushort* Gn     = (ushort*)ws;                       // 512 KB
  ushort* Wvbf   = (ushort*)(ws + 524288);            // 128 KB
  float*  numden = (float*)(ws + 524288 + 131072);    // 8 KB
  float*  num    = numden;
  float*  den    = numden + BATCH * OUTD;

  prep_all<<<97, 256, 0, stream>>>(query, Wq, bq, Wk, Wv, Gn, Wvbf, numden);
  attn_main<<<BATCH * BPB, 1024, 0, stream>>>(input, Gn, Wvbf, num, den);
  finalize<<<BATCH, 256, 0, stream>>>(num, den, bv, out);
}

// Round 7
// 158.563 us; speedup vs baseline: 2.5529x; 2.5529x over previous
//
#include <hip/hip_runtime.h>
#include <hip/hip_bf16.h>
#include <stdint.h>

using f32x4  = __attribute__((ext_vector_type(4))) float;
using f32x16 = __attribute__((ext_vector_type(16))) float;
using bf16x8 = __attribute__((ext_vector_type(8))) short;

constexpr int BATCH = 4;
constexpr int LQ_   = 256;
constexpr int LK_   = 50000;
constexpr int OUTD  = 256;
constexpr int EIN   = 128;
constexpr int KB    = 64;                     // k-rows per tile
constexpr int NKB   = (LK_ + KB - 1) / KB;    // 782
constexpr int BPB   = 128;                    // blocks per batch (grid = 512, 2/CU)

__device__ __forceinline__ uint32_t f2bf(float f) {
  uint32_t u = __builtin_bit_cast(uint32_t, f);
  u = (u + 0x7fffu + ((u >> 16) & 1u)) >> 16;
  return u;
}

// LDS-only barrier: drains this wave's LDS ops, then raw s_barrier.
// Does NOT drain vmcnt -> in-flight global prefetch survives the barrier.
__device__ __forceinline__ void block_sync_lds() {
  asm volatile("s_waitcnt lgkmcnt(0)" ::: "memory");
  __builtin_amdgcn_sched_barrier(0);
  __builtin_amdgcn_s_barrier();
  __builtin_amdgcn_sched_barrier(0);
}

// ---- prep_all: blocks 0-63 -> Gn, 64-95 -> cast Wv, 96 -> zero num/den ----
__global__ __launch_bounds__(256) void prep_all(
    const float* __restrict__ query, const float* __restrict__ Wq,
    const float* __restrict__ bq,    const float* __restrict__ Wk,
    const float* __restrict__ Wv,    ushort* __restrict__ Gn,
    ushort* __restrict__ Wvbf,       float* __restrict__ numden)
{
  const int blk = blockIdx.x, tid = threadIdx.x;
  if (blk >= 64) {
    if (blk < 96) {                       // cast Wv -> bf16 (32 blocks x 2048)
      int base = (blk - 64) * 2048 + tid * 8;
      float4 a = *(const float4*)(Wv + base);
      float4 c = *(const float4*)(Wv + base + 4);
      uint4 pk;
      pk.x = f2bf(a.x) | (f2bf(a.y) << 16);
      pk.y = f2bf(a.z) | (f2bf(a.w) << 16);
      pk.z = f2bf(c.x) | (f2bf(c.y) << 16);
      pk.w = f2bf(c.z) | (f2bf(c.w) << 16);
      *(uint4*)(Wvbf + base) = pk;
    } else {                              // zero the atomic accumulators
      for (int i = tid; i < 2 * BATCH * OUTD; i += 256) numden[i] = 0.f;
    }
    return;
  }
  // ---- Gn[b] = (1/16)*(query[b]@Wq^T + bq)@Wk, 16 q-rows per block -------
  __shared__ float qin[16 * EIN];
  __shared__ float Qr [16 * OUTD];
  const int b = blk >> 4, q0 = (blk & 15) * 16;
  {
    int idx = tid * 8;
    int row = idx >> 7, c = idx & 127;
    const float* p = query + ((size_t)b * LQ_ + q0 + row) * EIN + c;
    float4 a = *(const float4*)p;
    float4 d = *(const float4*)(p + 4);
    float* q = &qin[row * EIN + c];
    q[0]=a.x; q[1]=a.y; q[2]=a.z; q[3]=a.w; q[4]=d.x; q[5]=d.y; q[6]=d.z; q[7]=d.w;
  }
  __syncthreads();

  float acc[16];
  {
    float bias = bq[tid];
#pragma unroll
    for (int i = 0; i < 16; ++i) acc[i] = bias;
  }
  for (int d4 = 0; d4 < EIN / 4; ++d4) {
    f32x4 w4 = *(const f32x4*)(Wq + tid * EIN + d4 * 4);
#pragma unroll
    for (int i = 0; i < 16; ++i) {
      f32x4 q4 = *(const f32x4*)(qin + i * EIN + d4 * 4);
      acc[i] += q4[0]*w4[0] + q4[1]*w4[1] + q4[2]*w4[2] + q4[3]*w4[3];
    }
  }
#pragma unroll
  for (int i = 0; i < 16; ++i) Qr[i * OUTD + tid] = acc[i];
  __syncthreads();

  float acc2[16];
#pragma unroll
  for (int i = 0; i < 16; ++i) acc2[i] = 0.f;
  for (int d4 = 0; d4 < OUTD / 4; ++d4) {
    float w0 = Wk[(d4*4+0) * OUTD + tid];
    float w1 = Wk[(d4*4+1) * OUTD + tid];
    float w2 = Wk[(d4*4+2) * OUTD + tid];
    float w3 = Wk[(d4*4+3) * OUTD + tid];
#pragma unroll
    for (int i = 0; i < 16; ++i) {
      f32x4 q4 = *(const f32x4*)(Qr + i * OUTD + d4 * 4);
      acc2[i] += q4[0]*w0 + q4[1]*w1 + q4[2]*w2 + q4[3]*w3;
    }
  }
  const float norm = 0.0625f;
#pragma unroll
  for (int i = 0; i < 16; ++i)
    Gn[((size_t)b * LQ_ + q0 + i) * OUTD + tid] = (ushort)f2bf(acc2[i] * norm);
}

// ---- main ------------------------------------------------------------------
// 512 blocks (2/CU), 512 thr (8 waves). Wave w owns q-rows [w*32, w*32+32).
// R4 structure (reg-staged bf16, XOR-swizzled feature-major LDS) with the
// barrier replaced by an lgkm-only sync: global prefetch (issued a full
// iteration ahead) is never drained at barriers -> compute/memory overlap.
__global__ __launch_bounds__(512, 2) void attn_main(
    const float*  __restrict__ input, const ushort* __restrict__ Gn,
    const ushort* __restrict__ Wvbf,  float* __restrict__ num,
    float* __restrict__ den)
{
  __shared__ ushort lds[2 * 16384];   // 2 x 32 KB bf16
  const int b = blockIdx.x >> 7, blk = blockIdx.x & (BPB - 1);
  const int t0 = (blk * NKB) >> 7, t1 = ((blk + 1) * NKB) >> 7;
  const int tid = threadIdx.x, w = tid >> 6, l = tid & 63;
  const float* src = input + (size_t)b * LK_ * 256;

  // persistent A fragments (Gn for S-gemm, Wv for V-gemm), 16 K-steps each
  const int arow = w * 32 + (l & 31);
  const int hi = l >> 5;
  const ushort* gp = Gn   + ((size_t)b * LQ_ + arow) * 256 + hi * 8;
  const ushort* vp = Wvbf + (size_t)arow * 256 + hi * 8;
  bf16x8 ga[16], wa[16];
#pragma unroll
  for (int k = 0; k < 16; ++k) {
    ga[k] = *(const bf16x8*)(gp + k * 16);
    wa[k] = *(const bf16x8*)(vp + k * 16);
  }

  float numr[16], denr[16];
#pragma unroll
  for (int r = 0; r < 16; ++r) { numr[r] = 0.f; denr[r] = 0.f; }

  // staging regs: 4 granules x 32B (granule g = i*512+tid: row=g>>5, fb=g&31)
  float4 rga[4], rgb[4];
  auto loadreg = [&](int t) {
#pragma unroll
    for (int i = 0; i < 4; ++i) {
      int g = i * 512 + tid;
      int row = t * KB + (g >> 5);
      row = row < LK_ ? row : LK_ - 1;           // clamp (masked in epilogue)
      const float* p = src + (size_t)row * 256 + (g & 31) * 8;
      rga[i] = *(const float4*)p;
      rgb[i] = *(const float4*)(p + 4);
    }
  };
  auto writebuf = [&](int buf) {
    char* base = (char*)lds + buf * 32768;
#pragma unroll
    for (int i = 0; i < 4; ++i) {
      int g = i * 512 + tid;
      int row = g >> 5, fb = g & 31;
      uint4 pk;
      pk.x = f2bf(rga[i].x) | (f2bf(rga[i].y) << 16);
      pk.y = f2bf(rga[i].z) | (f2bf(rga[i].w) << 16);
      pk.z = f2bf(rgb[i].x) | (f2bf(rgb[i].y) << 16);
      pk.w = f2bf(rgb[i].z) | (f2bf(rgb[i].w) << 16);
      *(uint4*)(base + fb * 1024 + ((row ^ (fb & 7)) * 16)) = pk;
    }
  };

  loadreg(t0);
  writebuf(0);
  if (t0 + 1 < t1) loadreg(t0 + 1);   // stays in flight across the barrier
  block_sync_lds();

  for (int t = t0; t < t1; ++t) {
    const int p = (t - t0) & 1;
    if (t + 1 < t1) {
      writebuf(p ^ 1);                 // reg-dep vmcnt waits only on t+1 loads
      if (t + 2 < t1) loadreg(t + 2);  // issued now, lands during compute+next
    }
    const char* base = (const char*)lds + p * 32768;

#pragma unroll 1
    for (int ct = 0; ct < 2; ++ct) {
      f32x16 aS = {0,0,0,0,0,0,0,0,0,0,0,0,0,0,0,0};
      f32x16 aV = {0,0,0,0,0,0,0,0,0,0,0,0,0,0,0,0};
      const int r = ct * 32 + (l & 31);
#pragma unroll
      for (int ks = 0; ks < 16; ++ks) {
        const int fb = ks * 2 + hi;
        bf16x8 bb = *(const bf16x8*)(base + fb * 1024 + ((r ^ (fb & 7)) * 16));
        aS = __builtin_amdgcn_mfma_f32_32x32x16_bf16(ga[ks], bb, aS, 0, 0, 0);
        aV = __builtin_amdgcn_mfma_f32_32x32x16_bf16(wa[ks], bb, aV, 0, 0, 0);
      }
      const int krow = t * KB + r;
      const bool valid = krow < LK_;
#pragma unroll
      for (int rr = 0; rr < 16; ++rr) {
        float e = valid ? __expf(aS[rr]) : 0.f;
        denr[rr] += e;
        numr[rr] += e * aV[rr];
      }
    }
    block_sync_lds();   // lgkm-only: write(t+1)->read(t+1) and read(t)->write(t+2) safe
  }

  // reduce over the 32 k-columns, then one atomic per (q, {num,den})
#pragma unroll
  for (int r = 0; r < 16; ++r) {
    float d_ = denr[r], n_ = numr[r];
#pragma unroll
    for (int m = 1; m < 32; m <<= 1) {
      d_ += __shfl_xor(d_, m, 64);
      n_ += __shfl_xor(n_, m, 64);
    }
    if ((l & 31) == 0) {
      int q = w * 32 + (r & 3) + 8 * (r >> 2) + 4 * hi;
      atomicAdd(&den[b * OUTD + q], d_);
      atomicAdd(&num[b * OUTD + q], n_);
    }
  }
}

// ---- finalize: out = num/den + bv ------------------------------------------
__global__ __launch_bounds__(256) void finalize(const float* __restrict__ num,
                                                const float* __restrict__ den,
                                                const float* __restrict__ bv,
                                                float* __restrict__ out) {
  int i = blockIdx.x * 256 + threadIdx.x;
  out[i] = num[i] / den[i] + bv[i & 255];
}

extern "C" void kernel_launch(void* const* d_in, const int* in_sizes, int n_in,
                              void* d_out, int out_size, void* d_ws, size_t ws_size,
                              hipStream_t stream)
{
  const float* query = (const float*)d_in[0];
  const float* input = (const float*)d_in[1];
  const float* Wq    = (const float*)d_in[2];
  const float* bq    = (const float*)d_in[3];
  const float* Wk    = (const float*)d_in[4];
  // d_in[5] = bk : softmax-invariant, unused
  const float* Wv    = (const float*)d_in[6];
  const float* bv    = (const float*)d_in[7];
  float* out = (float*)d_out;

  char* ws = (char*)d_ws;
  ushort* Gn     = (ushort*)ws;                       // 512 KB
  ushort* Wvbf   = (ushort*)(ws + 524288);            // 128 KB
  float*  numden = (float*)(ws + 524288 + 131072);    // 8 KB
  float*  num    = numden;
  float*  den    = numden + BATCH * OUTD;

  prep_all<<<97, 256, 0, stream>>>(query, Wq, bq, Wk, Wv, Gn, Wvbf, numden);
  attn_main<<<BATCH * BPB, 512, 0, stream>>>(input, Gn, Wvbf, num, den);
  finalize<<<BATCH, 256, 0, stream>>>(num, den, bv, out);
}

// Round 8
// 146.530 us; speedup vs baseline: 2.7625x; 1.0821x over previous
//
#include <hip/hip_runtime.h>
#include <hip/hip_bf16.h>
#include <stdint.h>

using f32x4  = __attribute__((ext_vector_type(4))) float;
using f32x16 = __attribute__((ext_vector_type(16))) float;
using bf16x8 = __attribute__((ext_vector_type(8))) short;

constexpr int BATCH = 4;
constexpr int LQ_   = 256;
constexpr int LK_   = 50000;
constexpr int OUTD  = 256;
constexpr int EIN   = 128;
constexpr int TR    = 32;                      // k-rows per tile
constexpr int NT    = (LK_ + TR - 1) / TR;     // 1563 tiles of 32 rows
constexpr int KCH   = 32;                      // k-chunks per (b,qb)

__device__ __forceinline__ uint32_t f2bf(float f) {
  uint32_t u = __builtin_bit_cast(uint32_t, f);
  u = (u + 0x7fffu + ((u >> 16) & 1u)) >> 16;
  return u;
}

// LDS-only barrier: drains this wave's LDS ops, raw s_barrier, no vmcnt drain.
__device__ __forceinline__ void block_sync_lds() {
  asm volatile("s_waitcnt lgkmcnt(0)" ::: "memory");
  __builtin_amdgcn_sched_barrier(0);
  __builtin_amdgcn_s_barrier();
  __builtin_amdgcn_sched_barrier(0);
}

// ---- prep_all: blocks 0-63 -> Gn, 64-95 -> cast Wv, 96 -> zero num/den ----
__global__ __launch_bounds__(256) void prep_all(
    const float* __restrict__ query, const float* __restrict__ Wq,
    const float* __restrict__ bq,    const float* __restrict__ Wk,
    const float* __restrict__ Wv,    ushort* __restrict__ Gn,
    ushort* __restrict__ Wvbf,       float* __restrict__ numden)
{
  const int blk = blockIdx.x, tid = threadIdx.x;
  if (blk >= 64) {
    if (blk < 96) {                       // cast Wv -> bf16 (32 blocks x 2048)
      int base = (blk - 64) * 2048 + tid * 8;
      float4 a = *(const float4*)(Wv + base);
      float4 c = *(const float4*)(Wv + base + 4);
      uint4 pk;
      pk.x = f2bf(a.x) | (f2bf(a.y) << 16);
      pk.y = f2bf(a.z) | (f2bf(a.w) << 16);
      pk.z = f2bf(c.x) | (f2bf(c.y) << 16);
      pk.w = f2bf(c.z) | (f2bf(c.w) << 16);
      *(uint4*)(Wvbf + base) = pk;
    } else {                              // zero the atomic accumulators
      for (int i = tid; i < 2 * BATCH * OUTD; i += 256) numden[i] = 0.f;
    }
    return;
  }
  // ---- Gn[b] = (1/16)*(query[b]@Wq^T + bq)@Wk, 16 q-rows per block -------
  __shared__ float qin[16 * EIN];
  __shared__ float Qr [16 * OUTD];
  const int b = blk >> 4, q0 = (blk & 15) * 16;
  {
    int idx = tid * 8;
    int row = idx >> 7, c = idx & 127;
    const float* p = query + ((size_t)b * LQ_ + q0 + row) * EIN + c;
    float4 a = *(const float4*)p;
    float4 d = *(const float4*)(p + 4);
    float* q = &qin[row * EIN + c];
    q[0]=a.x; q[1]=a.y; q[2]=a.z; q[3]=a.w; q[4]=d.x; q[5]=d.y; q[6]=d.z; q[7]=d.w;
  }
  __syncthreads();

  float acc[16];
  {
    float bias = bq[tid];
#pragma unroll
    for (int i = 0; i < 16; ++i) acc[i] = bias;
  }
  for (int d4 = 0; d4 < EIN / 4; ++d4) {
    f32x4 w4 = *(const f32x4*)(Wq + tid * EIN + d4 * 4);
#pragma unroll
    for (int i = 0; i < 16; ++i) {
      f32x4 q4 = *(const f32x4*)(qin + i * EIN + d4 * 4);
      acc[i] += q4[0]*w4[0] + q4[1]*w4[1] + q4[2]*w4[2] + q4[3]*w4[3];
    }
  }
#pragma unroll
  for (int i = 0; i < 16; ++i) Qr[i * OUTD + tid] = acc[i];
  __syncthreads();

  float acc2[16];
#pragma unroll
  for (int i = 0; i < 16; ++i) acc2[i] = 0.f;
  for (int d4 = 0; d4 < OUTD / 4; ++d4) {
    float w0 = Wk[(d4*4+0) * OUTD + tid];
    float w1 = Wk[(d4*4+1) * OUTD + tid];
    float w2 = Wk[(d4*4+2) * OUTD + tid];
    float w3 = Wk[(d4*4+3) * OUTD + tid];
#pragma unroll
    for (int i = 0; i < 16; ++i) {
      f32x4 q4 = *(const f32x4*)(Qr + i * OUTD + d4 * 4);
      acc2[i] += q4[0]*w0 + q4[1]*w1 + q4[2]*w2 + q4[3]*w3;
    }
  }
  const float norm = 0.0625f;
#pragma unroll
  for (int i = 0; i < 16; ++i)
    Gn[((size_t)b * LQ_ + q0 + i) * OUTD + tid] = (ushort)f2bf(acc2[i] * norm);
}

// ---- main ------------------------------------------------------------------
// 256 blocks (1/CU), 256 thr = 4 waves. Block = (b, qb half of 128 q, kch).
// Wave qt owns q-rows qb*128 + qt*32 + [0,32). Gn slice lives in LDS (64 KB,
// swizzled granules) -> A-frags via ds_read_b128, NOT global (kills the L2
// latency chain that bound R2-R7). Wv frags in regs with NO occupancy cap
// (launch_bounds(256,1): ~500 VGPR budget -> allocator keeps them resident).
// Input: 32-row tiles, reg-staged, bf16 feature-major swizzled LDS, dbuf,
// ONE lgkm-only barrier per iter; global prefetch never drained at barriers.
__global__ __launch_bounds__(256, 1) void attn_main(
    const float*  __restrict__ input, const ushort* __restrict__ Gn,
    const ushort* __restrict__ Wvbf,  float* __restrict__ num,
    float* __restrict__ den)
{
  __shared__ ushort gn_lds[32768];    // 64 KB Gn[qb] slice, swizzled
  __shared__ ushort in_lds[2 * 8192]; // 2 x 16 KB input tile (bf16)
  const int idx = blockIdx.x;
  const int b = idx >> 6, qb = (idx >> 5) & 1, kch = idx & 31;
  const int t0 = (kch * NT) >> 5, t1 = ((kch + 1) * NT) >> 5;
  const int tid = threadIdx.x, qt = tid >> 6, l = tid & 63;
  const int hi = l >> 5, lr = l & 31;
  const float* src = input + (size_t)b * LK_ * 256;
  const ushort* GnB = Gn + (size_t)b * LQ_ * 256 + (size_t)qb * 128 * 256;

  // Wv fragments in registers (one matrix slice per wave: 64 VGPR)
  const int vrow = qb * 128 + qt * 32 + lr;
  const ushort* wp = Wvbf + (size_t)vrow * 256 + hi * 8;
  bf16x8 wa[16];
#pragma unroll
  for (int k = 0; k < 16; ++k) wa[k] = *(const bf16x8*)(wp + k * 16);

  // Fill Gn LDS: granule (row 0..127, gr 0..31) at row*512 + ((gr^ (row&31))<<4)
#pragma unroll
  for (int i = 0; i < 16; ++i) {
    int g2 = i * 256 + tid;
    int row = g2 >> 5, gr = g2 & 31;
    uint4 v = *(const uint4*)(GnB + row * 256 + gr * 8);
    *(uint4*)((char*)gn_lds + row * 512 + ((gr ^ (row & 31)) << 4)) = v;
  }

  float numr[16], denr[16];
#pragma unroll
  for (int r = 0; r < 16; ++r) { numr[r] = 0.f; denr[r] = 0.f; }

  // input staging: 4 granules/thread (g = i*256+tid: row=g>>5, fb=g&31)
  float4 rga[4], rgb[4];
  auto loadreg = [&](int t) {
#pragma unroll
    for (int i = 0; i < 4; ++i) {
      int g = i * 256 + tid;
      int row = t * TR + (g >> 5);
      row = row < LK_ ? row : LK_ - 1;   // clamp; masked via e=0
      const float* p = src + (size_t)row * 256 + (g & 31) * 8;
      rga[i] = *(const float4*)p;
      rgb[i] = *(const float4*)(p + 4);
    }
  };
  auto writebuf = [&](int buf) {
    char* base = (char*)in_lds + buf * 16384;
#pragma unroll
    for (int i = 0; i < 4; ++i) {
      int g = i * 256 + tid;
      int row = g >> 5, fb = g & 31;
      uint4 pk;
      pk.x = f2bf(rga[i].x) | (f2bf(rga[i].y) << 16);
      pk.y = f2bf(rga[i].z) | (f2bf(rga[i].w) << 16);
      pk.z = f2bf(rgb[i].x) | (f2bf(rgb[i].y) << 16);
      pk.w = f2bf(rgb[i].z) | (f2bf(rgb[i].w) << 16);
      *(uint4*)(base + fb * 512 + ((row ^ fb) << 4)) = pk;
    }
  };

  loadreg(t0);
  writebuf(t0 & 1);
  loadreg(t0 + 1);                      // in flight across barrier
  block_sync_lds();

  const char* arow_base = (const char*)gn_lds + (qt * 32 + lr) * 512;

  for (int t = t0; t < t1; ++t) {
    // ---- compute(t): reads buf[t&1] (written last iter) + Gn LDS ----
    const char* bbuf = (const char*)in_lds + (t & 1) * 16384;
    f32x16 aS = {0,0,0,0,0,0,0,0,0,0,0,0,0,0,0,0};
    f32x16 aV = {0,0,0,0,0,0,0,0,0,0,0,0,0,0,0,0};
#pragma unroll
    for (int ks = 0; ks < 16; ++ks) {
      const int gr = ks * 2 + hi;
      bf16x8 ga = *(const bf16x8*)(arow_base + ((gr ^ lr) << 4));
      bf16x8 bb = *(const bf16x8*)(bbuf + gr * 512 + ((lr ^ gr) << 4));
      aS = __builtin_amdgcn_mfma_f32_32x32x16_bf16(ga, bb, aS, 0, 0, 0);
      aV = __builtin_amdgcn_mfma_f32_32x32x16_bf16(wa[ks], bb, aV, 0, 0, 0);
    }
    {
      const bool valid = (t * TR + lr) < LK_;
#pragma unroll
      for (int r = 0; r < 16; ++r) {
        float e = valid ? __expf(aS[r]) : 0.f;
        denr[r] += e;
        numr[r] += e * aV[r];
      }
    }
    // ---- stage: drain regs(t+1) -> buf[(t+1)&1]; issue loads(t+2) ----
    if (t + 1 < t1) {
      writebuf((t + 1) & 1);            // vmcnt-dep on loads issued last iter
      if (t + 2 < t1) loadreg(t + 2);
    }
    block_sync_lds();                   // single lgkm-only barrier per iter
  }

  // reduce over the 32 k-columns, then one atomic per (q, {num,den})
#pragma unroll
  for (int r = 0; r < 16; ++r) {
    float d_ = denr[r], n_ = numr[r];
#pragma unroll
    for (int m = 1; m < 32; m <<= 1) {
      d_ += __shfl_xor(d_, m, 64);
      n_ += __shfl_xor(n_, m, 64);
    }
    if (lr == 0) {
      int q = qb * 128 + qt * 32 + (r & 3) + 8 * (r >> 2) + 4 * hi;
      atomicAdd(&den[b * OUTD + q], d_);
      atomicAdd(&num[b * OUTD + q], n_);
    }
  }
}

// ---- finalize: out = num/den + bv ------------------------------------------
__global__ __launch_bounds__(256) void finalize(const float* __restrict__ num,
                                                const float* __restrict__ den,
                                                const float* __restrict__ bv,
                                                float* __restrict__ out) {
  int i = blockIdx.x * 256 + threadIdx.x;
  out[i] = num[i] / den[i] + bv[i & 255];
}

extern "C" void kernel_launch(void* const* d_in, const int* in_sizes, int n_in,
                              void* d_out, int out_size, void* d_ws, size_t ws_size,
                              hipStream_t stream)
{
  const float* query = (const float*)d_in[0];
  const float* input = (const float*)d_in[1];
  const float* Wq    = (const float*)d_in[2];
  const float* bq    = (const float*)d_in[3];
  const float* Wk    = (const float*)d_in[4];
  // d_in[5] = bk : softmax-invariant, unused
  const float* Wv    = (const float*)d_in[6];
  const float* bv    = (const float*)d_in[7];
  float* out = (float*)d_out;

  char* ws = (char*)d_ws;
  ushort* Gn     = (ushort*)ws;                       // 512 KB
  ushort* Wvbf   = (ushort*)(ws + 524288);            // 128 KB
  float*  numden = (float*)(ws + 524288 + 131072);    // 8 KB
  float*  num    = numden;
  float*  den    = numden + BATCH * OUTD;

  prep_all<<<97, 256, 0, stream>>>(query, Wq, bq, Wk, Wv, Gn, Wvbf, numden);
  attn_main<<<BATCH * 2 * KCH, 256, 0, stream>>>(input, Gn, Wvbf, num, den);
  finalize<<<BATCH, 256, 0, stream>>>(num, den, bv, out);
}

// Round 9
// 120.429 us; speedup vs baseline: 3.3612x; 1.2167x over previous
//
#include <hip/hip_runtime.h>
#include <hip/hip_bf16.h>
#include <stdint.h>

using f32x4  = __attribute__((ext_vector_type(4))) float;
using f32x16 = __attribute__((ext_vector_type(16))) float;
using bf16x8 = __attribute__((ext_vector_type(8))) short;

constexpr int BATCH = 4;
constexpr int LQ_   = 256;
constexpr int LK_   = 50000;
constexpr int OUTD  = 256;
constexpr int EIN   = 128;
constexpr int TR    = 32;                      // k-rows per tile
constexpr int NT    = (LK_ + TR - 1) / TR;     // 1563 tiles
constexpr int KCH   = 64;                      // k-chunks per batch

__device__ __forceinline__ uint32_t f2bf(float f) {
  uint32_t u = __builtin_bit_cast(uint32_t, f);
  u = (u + 0x7fffu + ((u >> 16) & 1u)) >> 16;
  return u;
}

// LDS-only barrier: drains this wave's LDS ops, raw s_barrier, no vmcnt drain.
__device__ __forceinline__ void block_sync_lds() {
  asm volatile("s_waitcnt lgkmcnt(0)" ::: "memory");
  __builtin_amdgcn_sched_barrier(0);
  __builtin_amdgcn_s_barrier();
  __builtin_amdgcn_sched_barrier(0);
}

// ---- prep_all: blocks 0-63 -> Gn, 64-95 -> cast Wv, 96 -> zero num/den ----
__global__ __launch_bounds__(256) void prep_all(
    const float* __restrict__ query, const float* __restrict__ Wq,
    const float* __restrict__ bq,    const float* __restrict__ Wk,
    const float* __restrict__ Wv,    ushort* __restrict__ Gn,
    ushort* __restrict__ Wvbf,       float* __restrict__ numden)
{
  const int blk = blockIdx.x, tid = threadIdx.x;
  if (blk >= 64) {
    if (blk < 96) {                       // cast Wv -> bf16 (32 blocks x 2048)
      int base = (blk - 64) * 2048 + tid * 8;
      float4 a = *(const float4*)(Wv + base);
      float4 c = *(const float4*)(Wv + base + 4);
      uint4 pk;
      pk.x = f2bf(a.x) | (f2bf(a.y) << 16);
      pk.y = f2bf(a.z) | (f2bf(a.w) << 16);
      pk.z = f2bf(c.x) | (f2bf(c.y) << 16);
      pk.w = f2bf(c.z) | (f2bf(c.w) << 16);
      *(uint4*)(Wvbf + base) = pk;
    } else {                              // zero the atomic accumulators
      for (int i = tid; i < 2 * BATCH * OUTD; i += 256) numden[i] = 0.f;
    }
    return;
  }
  // ---- Gn[b] = (1/16)*(query[b]@Wq^T + bq)@Wk, 16 q-rows per block -------
  __shared__ float qin[16 * EIN];
  __shared__ float Qr [16 * OUTD];
  const int b = blk >> 4, q0 = (blk & 15) * 16;
  {
    int idx = tid * 8;
    int row = idx >> 7, c = idx & 127;
    const float* p = query + ((size_t)b * LQ_ + q0 + row) * EIN + c;
    float4 a = *(const float4*)p;
    float4 d = *(const float4*)(p + 4);
    float* q = &qin[row * EIN + c];
    q[0]=a.x; q[1]=a.y; q[2]=a.z; q[3]=a.w; q[4]=d.x; q[5]=d.y; q[6]=d.z; q[7]=d.w;
  }
  __syncthreads();

  float acc[16];
  {
    float bias = bq[tid];
#pragma unroll
    for (int i = 0; i < 16; ++i) acc[i] = bias;
  }
  for (int d4 = 0; d4 < EIN / 4; ++d4) {
    f32x4 w4 = *(const f32x4*)(Wq + tid * EIN + d4 * 4);
#pragma unroll
    for (int i = 0; i < 16; ++i) {
      f32x4 q4 = *(const f32x4*)(qin + i * EIN + d4 * 4);
      acc[i] += q4[0]*w4[0] + q4[1]*w4[1] + q4[2]*w4[2] + q4[3]*w4[3];
    }
  }
#pragma unroll
  for (int i = 0; i < 16; ++i) Qr[i * OUTD + tid] = acc[i];
  __syncthreads();

  float acc2[16];
#pragma unroll
  for (int i = 0; i < 16; ++i) acc2[i] = 0.f;
  for (int d4 = 0; d4 < OUTD / 4; ++d4) {
    float w0 = Wk[(d4*4+0) * OUTD + tid];
    float w1 = Wk[(d4*4+1) * OUTD + tid];
    float w2 = Wk[(d4*4+2) * OUTD + tid];
    float w3 = Wk[(d4*4+3) * OUTD + tid];
#pragma unroll
    for (int i = 0; i < 16; ++i) {
      f32x4 q4 = *(const f32x4*)(Qr + i * OUTD + d4 * 4);
      acc2[i] += q4[0]*w0 + q4[1]*w1 + q4[2]*w2 + q4[3]*w3;
    }
  }
  const float norm = 0.0625f;
#pragma unroll
  for (int i = 0; i < 16; ++i)
    Gn[((size_t)b * LQ_ + q0 + i) * OUTD + tid] = (ushort)f2bf(acc2[i] * norm);
}

// ---- main ------------------------------------------------------------------
// 256 blocks (1/CU), 512 thr = 8 waves; block = (batch b, k-chunk). Wave w
// owns q-rows [w*32, w*32+32) -> block covers ALL 256 q -> input read ONCE.
// Gn+Wv fragments both live in regs, asm-pinned (128 VGPR); launch_bounds
// (512,1) removes the register cap so the allocator cannot demote them to
// in-loop global reloads (the R2-R8 pathology). Actual use ~225 regs -> 2
// waves/SIMD. LDS = input dbuf only (2 x 16 KB bf16, feature-major granules
// swizzled (row^fb)<<4: write and read both bank-uniform). One lgkm-only
// barrier per iter; global prefetch issued 2 tiles ahead, never drained.
__global__ __launch_bounds__(512, 1) void attn_main(
    const float*  __restrict__ input, const ushort* __restrict__ Gn,
    const ushort* __restrict__ Wvbf,  float* __restrict__ num,
    float* __restrict__ den)
{
  __shared__ ushort in_lds[2 * 8192]; // 2 x 16 KB
  const int idx = blockIdx.x;
  const int b = idx >> 6, kch = idx & (KCH - 1);
  const int t0 = (kch * NT) >> 6, t1 = ((kch + 1) * NT) >> 6;
  const int tid = threadIdx.x, w = tid >> 6, l = tid & 63;
  const int hi = l >> 5, lr = l & 31;
  const float* src = input + (size_t)b * LK_ * 256;

  // persistent A fragments for BOTH gemms (this wave's 32 q-rows), pinned
  const int arow = w * 32 + lr;
  const ushort* gp = Gn   + ((size_t)b * LQ_ + arow) * 256 + hi * 8;
  const ushort* vp = Wvbf + (size_t)arow * 256 + hi * 8;
  bf16x8 ga[16], wa[16];
#pragma unroll
  for (int k = 0; k < 16; ++k) {
    ga[k] = *(const bf16x8*)(gp + k * 16);
    wa[k] = *(const bf16x8*)(vp + k * 16);
    asm volatile("" : "+v"(ga[k]), "+v"(wa[k]));  // forbid remat/sink
  }

  float numr[16], denr[16];
#pragma unroll
  for (int r = 0; r < 16; ++r) { numr[r] = 0.f; denr[r] = 0.f; }

  // staging: thread handles 16 consecutive floats = granules (row, fb0|fb1)
  const int srow = tid >> 4;                 // 0..31
  const int sfb0 = (tid * 2) & 31;           // even fb
  float4 s0, s1, s2, s3;
  auto loadreg = [&](int t) {
    int r = t * TR + srow;
    r = r < LK_ ? r : LK_ - 1;               // clamp; masked via e=0
    const float* p = src + (size_t)r * 256 + sfb0 * 8;
    s0 = *(const float4*)p;
    s1 = *(const float4*)(p + 4);
    s2 = *(const float4*)(p + 8);
    s3 = *(const float4*)(p + 12);
  };
  auto writebuf = [&](int buf) {
    char* base = (char*)in_lds + buf * 16384;
    uint4 pk0, pk1;
    pk0.x = f2bf(s0.x) | (f2bf(s0.y) << 16);
    pk0.y = f2bf(s0.z) | (f2bf(s0.w) << 16);
    pk0.z = f2bf(s1.x) | (f2bf(s1.y) << 16);
    pk0.w = f2bf(s1.z) | (f2bf(s1.w) << 16);
    pk1.x = f2bf(s2.x) | (f2bf(s2.y) << 16);
    pk1.y = f2bf(s2.z) | (f2bf(s2.w) << 16);
    pk1.z = f2bf(s3.x) | (f2bf(s3.y) << 16);
    pk1.w = f2bf(s3.z) | (f2bf(s3.w) << 16);
    *(uint4*)(base + sfb0 * 512 + ((srow ^ sfb0) << 4)) = pk0;
    *(uint4*)(base + (sfb0 + 1) * 512 + ((srow ^ (sfb0 + 1)) << 4)) = pk1;
  };

  loadreg(t0);
  writebuf(t0 & 1);
  loadreg(t0 + 1);                  // in flight across the barrier
  block_sync_lds();

  for (int t = t0; t < t1; ++t) {
    // ---- compute(t) from buf[t&1] ----
    const char* bbuf = (const char*)in_lds + (t & 1) * 16384;
    f32x16 aS = {0,0,0,0,0,0,0,0,0,0,0,0,0,0,0,0};
    f32x16 aV = {0,0,0,0,0,0,0,0,0,0,0,0,0,0,0,0};
#pragma unroll
    for (int ks = 0; ks < 16; ++ks) {
      const int gr = ks * 2 + hi;
      bf16x8 bb = *(const bf16x8*)(bbuf + gr * 512 + ((lr ^ gr) << 4));
      aS = __builtin_amdgcn_mfma_f32_32x32x16_bf16(ga[ks], bb, aS, 0, 0, 0);
      aV = __builtin_amdgcn_mfma_f32_32x32x16_bf16(wa[ks], bb, aV, 0, 0, 0);
    }
    {
      const bool valid = (t * TR + lr) < LK_;
#pragma unroll
      for (int r = 0; r < 16; ++r) {
        float e = valid ? __expf(aS[r]) : 0.f;
        denr[r] += e;
        numr[r] += e * aV[r];
      }
    }
    // ---- stage: regs(t+1) -> buf[(t+1)&1]; issue loads(t+2) ----
    if (t + 1 < t1) {
      writebuf((t + 1) & 1);         // vmcnt-dep on loads issued last iter
      if (t + 2 < t1) loadreg(t + 2);
    }
    block_sync_lds();                // single lgkm-only barrier per iter
  }

  // reduce over the 32 k-columns, then one atomic per (q, {num,den})
#pragma unroll
  for (int r = 0; r < 16; ++r) {
    float d_ = denr[r], n_ = numr[r];
#pragma unroll
    for (int m = 1; m < 32; m <<= 1) {
      d_ += __shfl_xor(d_, m, 64);
      n_ += __shfl_xor(n_, m, 64);
    }
    if (lr == 0) {
      int q = w * 32 + (r & 3) + 8 * (r >> 2) + 4 * hi;
      atomicAdd(&den[b * OUTD + q], d_);
      atomicAdd(&num[b * OUTD + q], n_);
    }
  }
}

// ---- finalize: out = num/den + bv ------------------------------------------
__global__ __launch_bounds__(256) void finalize(const float* __restrict__ num,
                                                const float* __restrict__ den,
                                                const float* __restrict__ bv,
                                                float* __restrict__ out) {
  int i = blockIdx.x * 256 + threadIdx.x;
  out[i] = num[i] / den[i] + bv[i & 255];
}

extern "C" void kernel_launch(void* const* d_in, const int* in_sizes, int n_in,
                              void* d_out, int out_size, void* d_ws, size_t ws_size,
                              hipStream_t stream)
{
  const float* query = (const float*)d_in[0];
  const float* input = (const float*)d_in[1];
  const float* Wq    = (const float*)d_in[2];
  const float* bq    = (const float*)d_in[3];
  const float* Wk    = (const float*)d_in[4];
  // d_in[5] = bk : softmax-invariant, unused
  const float* Wv    = (const float*)d_in[6];
  const float* bv    = (const float*)d_in[7];
  float* out = (float*)d_out;

  char* ws = (char*)d_ws;
  ushort* Gn     = (ushort*)ws;                       // 512 KB
  ushort* Wvbf   = (ushort*)(ws + 524288);            // 128 KB
  float*  numden = (float*)(ws + 524288 + 131072);    // 8 KB
  float*  num    = numden;
  float*  den    = numden + BATCH * OUTD;

  prep_all<<<97, 256, 0, stream>>>(query, Wq, bq, Wk, Wv, Gn, Wvbf, numden);
  attn_main<<<BATCH * KCH, 512, 0, stream>>>(input, Gn, Wvbf, num, den);
  finalize<<<BATCH, 256, 0, stream>>>(num, den, bv, out);
}

// Round 11
// 105.564 us; speedup vs baseline: 3.8346x; 1.1408x over previous
//
#include <hip/hip_runtime.h>
#include <hip/hip_bf16.h>
#include <stdint.h>

using f32x4  = __attribute__((ext_vector_type(4))) float;
using bf16x8 = __attribute__((ext_vector_type(8))) short;

constexpr int BATCH = 4;
constexpr int LQ_   = 256;
constexpr int LK_   = 50000;
constexpr int OUTD  = 256;
constexpr int EIN   = 128;
constexpr int TR    = 16;                      // k-rows per tile
constexpr int NT    = LK_ / TR;                // 3125 (exact: no tail masking)
constexpr int KCH   = 64;                      // k-chunks per batch (grid 256 = 1/CU)

__device__ __forceinline__ uint32_t f2bf(float f) {
  uint32_t u = __builtin_bit_cast(uint32_t, f);
  u = (u + 0x7fffu + ((u >> 16) & 1u)) >> 16;
  return u;
}

// LDS-only barrier: drains this wave's LDS ops, raw s_barrier, no vmcnt drain.
__device__ __forceinline__ void block_sync_lds() {
  asm volatile("s_waitcnt lgkmcnt(0)" ::: "memory");
  __builtin_amdgcn_sched_barrier(0);
  __builtin_amdgcn_s_barrier();
  __builtin_amdgcn_sched_barrier(0);
}

// ---- prep_all: blocks 0-63 -> Gn, 64-95 -> cast Wv, 96 -> zero num/den ----
__global__ __launch_bounds__(256) void prep_all(
    const float* __restrict__ query, const float* __restrict__ Wq,
    const float* __restrict__ bq,    const float* __restrict__ Wk,
    const float* __restrict__ Wv,    ushort* __restrict__ Gn,
    ushort* __restrict__ Wvbf,       float* __restrict__ numden)
{
  const int blk = blockIdx.x, tid = threadIdx.x;
  if (blk >= 64) {
    if (blk < 96) {                       // cast Wv -> bf16 (32 blocks x 2048)
      int base = (blk - 64) * 2048 + tid * 8;
      float4 a = *(const float4*)(Wv + base);
      float4 c = *(const float4*)(Wv + base + 4);
      uint4 pk;
      pk.x = f2bf(a.x) | (f2bf(a.y) << 16);
      pk.y = f2bf(a.z) | (f2bf(a.w) << 16);
      pk.z = f2bf(c.x) | (f2bf(c.y) << 16);
      pk.w = f2bf(c.z) | (f2bf(c.w) << 16);
      *(uint4*)(Wvbf + base) = pk;
    } else {                              // zero the atomic accumulators
      for (int i = tid; i < 2 * BATCH * OUTD; i += 256) numden[i] = 0.f;
    }
    return;
  }
  // ---- Gn[b] = (1/16)*(query[b]@Wq^T + bq)@Wk, 16 q-rows per block -------
  __shared__ float qin[16 * EIN];
  __shared__ float Qr [16 * OUTD];
  const int b = blk >> 4, q0 = (blk & 15) * 16;
  {
    int idx = tid * 8;
    int row = idx >> 7, c = idx & 127;
    const float* p = query + ((size_t)b * LQ_ + q0 + row) * EIN + c;
    float4 a = *(const float4*)p;
    float4 d = *(const float4*)(p + 4);
    float* q = &qin[row * EIN + c];
    q[0]=a.x; q[1]=a.y; q[2]=a.z; q[3]=a.w; q[4]=d.x; q[5]=d.y; q[6]=d.z; q[7]=d.w;
  }
  __syncthreads();

  float acc[16];
  {
    float bias = bq[tid];
#pragma unroll
    for (int i = 0; i < 16; ++i) acc[i] = bias;
  }
  for (int d4 = 0; d4 < EIN / 4; ++d4) {
    f32x4 w4 = *(const f32x4*)(Wq + tid * EIN + d4 * 4);
#pragma unroll
    for (int i = 0; i < 16; ++i) {
      f32x4 q4 = *(const f32x4*)(qin + i * EIN + d4 * 4);
      acc[i] += q4[0]*w4[0] + q4[1]*w4[1] + q4[2]*w4[2] + q4[3]*w4[3];
    }
  }
#pragma unroll
  for (int i = 0; i < 16; ++i) Qr[i * OUTD + tid] = acc[i];
  __syncthreads();

  float acc2[16];
#pragma unroll
  for (int i = 0; i < 16; ++i) acc2[i] = 0.f;
  for (int d4 = 0; d4 < OUTD / 4; ++d4) {
    float w0 = Wk[(d4*4+0) * OUTD + tid];
    float w1 = Wk[(d4*4+1) * OUTD + tid];
    float w2 = Wk[(d4*4+2) * OUTD + tid];
    float w3 = Wk[(d4*4+3) * OUTD + tid];
#pragma unroll
    for (int i = 0; i < 16; ++i) {
      f32x4 q4 = *(const f32x4*)(Qr + i * OUTD + d4 * 4);
      acc2[i] += q4[0]*w0 + q4[1]*w1 + q4[2]*w2 + q4[3]*w3;
    }
  }
  const float norm = 0.0625f;
#pragma unroll
  for (int i = 0; i < 16; ++i)
    Gn[((size_t)b * LQ_ + q0 + i) * OUTD + tid] = (ushort)f2bf(acc2[i] * norm);
}

// ---- main ------------------------------------------------------------------
// 256 blocks (1/CU), 1024 thr = 16 waves; block = (b, k-chunk); wave w owns
// q-rows [w*16, w*16+16) -> 16 waves x 16 = ALL 256 q (R10's NaN was 8x16 =
// half coverage -> den=0 -> 0/0). A-frags 64 VGPR; total ~100 < 128 cap of
// launch_bounds(1024,4) -> 16 waves/CU (4/SIMD) without demotion pressure.
// TR=16: LK = 3125*16 exact -> no masks. LDS: 2 x 8 KB bf16 tile, granule
// (fbg 0..31, row 0..15) at fbg*256 + ((row^(fbg&15))<<4); staging thread =
// half-granule (h = tid&1): each wave loads one contiguous 1KB input row.
// Single lgkm-only barrier/iter; prefetch 2 tiles ahead, never drained.
__global__ __launch_bounds__(1024, 4) void attn_main(
    const float*  __restrict__ input, const ushort* __restrict__ Gn,
    const ushort* __restrict__ Wvbf,  float* __restrict__ num,
    float* __restrict__ den)
{
  __shared__ ushort in_lds[2 * 4096]; // 2 x 8 KB
  const int idx = blockIdx.x;
  const int b = idx >> 6, kch = idx & (KCH - 1);
  const int t0 = (kch * NT) >> 6, t1 = ((kch + 1) * NT) >> 6;
  const int tid = threadIdx.x, w = tid >> 6, l = tid & 63;
  const int lg = l >> 4, lr = l & 15;     // lane-group (k-features) / row
  const float* src = input + (size_t)b * LK_ * 256;

  // A-frags (16x16x32): q-row = w*16+lr, features ks*32 + lg*8 + [0,8)
  const int arow = w * 16 + lr;
  const ushort* gp = Gn   + ((size_t)b * LQ_ + arow) * 256 + lg * 8;
  const ushort* vp = Wvbf + (size_t)arow * 256 + lg * 8;
  bf16x8 ga[8], wa[8];
#pragma unroll
  for (int k = 0; k < 8; ++k) {
    ga[k] = *(const bf16x8*)(gp + k * 32);
    wa[k] = *(const bf16x8*)(vp + k * 32);
    asm volatile("" : "+v"(ga[k]), "+v"(wa[k]));  // forbid remat/sink
  }

  float numr[4], denr[4];
#pragma unroll
  for (int r = 0; r < 4; ++r) { numr[r] = 0.f; denr[r] = 0.f; }

  // staging: thread = half-granule. g = tid>>1: row = g>>5 (0..15),
  // fbg = g&31 (0..31), h = tid&1 -> f32 cols fbg*8 + h*4 .. +4.
  // Wave reads 1 contiguous KB (one input row); write = ds_write_b64.
  const int sg = tid >> 1, sh = tid & 1;
  const int srow = sg >> 5, sfbg = sg & 31;
  float4 s0;
  auto loadreg = [&](int t) {
    const float* p = src + (size_t)(t * TR + srow) * 256 + sfbg * 8 + sh * 4;
    s0 = *(const float4*)p;
  };
  auto writebuf = [&](int buf) {
    char* base = (char*)in_lds + buf * 8192;
    uint2 pk;
    pk.x = f2bf(s0.x) | (f2bf(s0.y) << 16);
    pk.y = f2bf(s0.z) | (f2bf(s0.w) << 16);
    *(uint2*)(base + sfbg * 256 + ((srow ^ (sfbg & 15)) << 4) + sh * 8) = pk;
  };

  loadreg(t0);
  writebuf(t0 & 1);
  loadreg(t0 + 1);                  // in flight across the barrier
  block_sync_lds();

  for (int t = t0; t < t1; ++t) {
    // ---- compute(t) from buf[t&1] ----
    const char* bbuf = (const char*)in_lds + (t & 1) * 8192;
    f32x4 aS = {0,0,0,0};
    f32x4 aV = {0,0,0,0};
#pragma unroll
    for (int ks = 0; ks < 8; ++ks) {
      const int fb = ks * 4 + lg;
      bf16x8 bb = *(const bf16x8*)(bbuf + fb * 256 + ((lr ^ (fb & 15)) << 4));
      aS = __builtin_amdgcn_mfma_f32_16x16x32_bf16(ga[ks], bb, aS, 0, 0, 0);
      aV = __builtin_amdgcn_mfma_f32_16x16x32_bf16(wa[ks], bb, aV, 0, 0, 0);
    }
#pragma unroll
    for (int r = 0; r < 4; ++r) {
      float e = __expf(aS[r]);      // no mask: 16 | LK exactly
      denr[r] += e;
      numr[r] += e * aV[r];
    }
    // ---- stage: regs(t+1) -> buf[(t+1)&1]; issue loads(t+2) ----
    if (t + 1 < t1) {
      writebuf((t + 1) & 1);        // vmcnt-dep only on loads issued last iter
      if (t + 2 < t1) loadreg(t + 2);
    }
    block_sync_lds();               // single lgkm-only barrier per iter
  }

  // reduce over the 16 k-columns (lanes lr), one atomic per (q, {num,den})
#pragma unroll
  for (int r = 0; r < 4; ++r) {
    float d_ = denr[r], n_ = numr[r];
#pragma unroll
    for (int m = 1; m < 16; m <<= 1) {
      d_ += __shfl_xor(d_, m, 64);
      n_ += __shfl_xor(n_, m, 64);
    }
    if (lr == 0) {
      int q = w * 16 + lg * 4 + r;  // D row = (lane>>4)*4 + reg
      atomicAdd(&den[b * OUTD + q], d_);
      atomicAdd(&num[b * OUTD + q], n_);
    }
  }
}

// ---- finalize: out = num/den + bv ------------------------------------------
__global__ __launch_bounds__(256) void finalize(const float* __restrict__ num,
                                                const float* __restrict__ den,
                                                const float* __restrict__ bv,
                                                float* __restrict__ out) {
  int i = blockIdx.x * 256 + threadIdx.x;
  out[i] = num[i] / den[i] + bv[i & 255];
}

extern "C" void kernel_launch(void* const* d_in, const int* in_sizes, int n_in,
                              void* d_out, int out_size, void* d_ws, size_t ws_size,
                              hipStream_t stream)
{
  const float* query = (const float*)d_in[0];
  const float* input = (const float*)d_in[1];
  const float* Wq    = (const float*)d_in[2];
  const float* bq    = (const float*)d_in[3];
  const float* Wk    = (const float*)d_in[4];
  // d_in[5] = bk : softmax-invariant, unused
  const float* Wv    = (const float*)d_in[6];
  const float* bv    = (const float*)d_in[7];
  float* out = (float*)d_out;

  char* ws = (char*)d_ws;
  ushort* Gn     = (ushort*)ws;                       // 512 KB
  ushort* Wvbf   = (ushort*)(ws + 524288);            // 128 KB
  float*  numden = (float*)(ws + 524288 + 131072);    // 8 KB
  float*  num    = numden;
  float*  den    = numden + BATCH * OUTD;

  prep_all<<<97, 256, 0, stream>>>(query, Wq, bq, Wk, Wv, Gn, Wvbf, numden);
  attn_main<<<BATCH * KCH, 1024, 0, stream>>>(input, Gn, Wvbf, num, den);
  finalize<<<BATCH, 256, 0, stream>>>(num, den, bv, out);
}